// Round 10
// baseline (1961.512 us; speedup 1.0000x reference)
//
#include <hip/hip_runtime.h>
#include <hip/hip_bf16.h>
#include <cstdint>
#include <cstddef>
#include <math.h>

// Match numpy f32 per-op rounding: no FMA contraction, no reassociation.
// (fmaf() below is explicit and unaffected by the pragma.)
#pragma clang fp contract(off)

#define A_N 8732
#define C_N 91
#define CM1 90
#define B_N 32
#define TOPK 400
#define MAXDET 200
#define NCAND (CM1 * TOPK)                  /* 36000 flat candidates per image */
#define BBOX_CLIPF 4.135166556742356f       /* log(1000/16) cast to f32 */

// Dual-path input load (reference is float32; sniff is insurance).
__device__ __forceinline__ float ldin(const void* p, size_t i, int isbf16) {
    if (isbf16) return __bfloat162float(((const __hip_bfloat16*)p)[i]);
    return ((const float*)p)[i];
}

// numpy SIMD f32 exp, bit-faithful to numpy's avx512_exp_FLOAT /
// simd_exp dispatch path:
//   quadrant = roundscale(x * log2e)  -> rint of the PRODUCT (half-even),
//   Cody-Waite 2-term reduction via fnmadd (c1=0.693359375, c2=-2.12194440e-4),
//   PURE degree-7 Horner with constants {p0..p5, 1.0, 1.0}  (NOT the
//   Eigen/Pommier p*r^2+r (+1) tail — that association differs in final bits),
//   scale = scalef(poly, quadrant) == ldexpf.
// Inputs here are in [-30, 4.2]: no clamp region.
__device__ __forceinline__ float np_expf(float x) {
    float q = rintf(x * 1.442695040f);
    float r = fmaf(q, -0.693359375f, x);
    r = fmaf(q, 2.12194440e-4f, r);
    float p = 1.9875691500E-4f;
    p = fmaf(p, r, 1.3981999507E-3f);
    p = fmaf(p, r, 8.3334519073E-3f);
    p = fmaf(p, r, 4.1665795894E-2f);
    p = fmaf(p, r, 1.6666665459E-1f);
    p = fmaf(p, r, 5.0000001201E-1f);
    p = fmaf(p, r, 1.0f);
    p = fmaf(p, r, 1.0f);
    return ldexpf(p, (int)q);
}

// ---------------------------------------------------------------- dtype sniff
__global__ void k_sniff(const unsigned* __restrict__ words, int* __restrict__ flag) {
    __shared__ int cnt_s;
    if (threadIdx.x == 0) cnt_s = 0;
    __syncthreads();
    int local = 0;
    for (int i = threadIdx.x; i < 4096; i += 256) {
        unsigned w = words[i];
        unsigned e = (w >> 7) & 0xFFu;
        if (e >= 100u && e <= 140u) local++;
    }
    atomicAdd(&cnt_s, local);
    __syncthreads();
    if (threadIdx.x == 0) flag[0] = (cnt_s > 2048) ? 1 : 0;
}

// ---------------------------------------------------------------- softmax stats
// denom = numpy pairwise_sum over the 91 f32 exp terms (n=91 <= blocksize:
// 8 accumulators over c<88, tree combine, sequential tail 88..90).
__global__ void k_stats(const void* __restrict__ logits,
                        const int* __restrict__ flag,
                        float* __restrict__ amax,
                        float* __restrict__ denom) {
    int i = blockIdx.x * blockDim.x + threadIdx.x;
    if (i >= B_N * A_N) return;
    int bf = flag[0];
    size_t base = (size_t)i * C_N;
    float m = -INFINITY;
    for (int c = 0; c < C_N; ++c) m = fmaxf(m, ldin(logits, base + c, bf));
    float r[8];
    for (int j = 0; j < 8; ++j) r[j] = np_expf(ldin(logits, base + j, bf) - m);
    for (int c = 8; c < 88; c += 8)
        for (int j = 0; j < 8; ++j) r[j] += np_expf(ldin(logits, base + c + j, bf) - m);
    float res = ((r[0] + r[1]) + (r[2] + r[3])) + ((r[4] + r[5]) + (r[6] + r[7]));
    res += np_expf(ldin(logits, base + 88, bf) - m);
    res += np_expf(ldin(logits, base + 89, bf) - m);
    res += np_expf(ldin(logits, base + 90, bf) - m);
    amax[i]  = m;
    denom[i] = res;
}

// ---------------------------------------------------------------- box decode (f32 literal, np exp)
__global__ void k_decode(const void* __restrict__ rel,
                         const void* __restrict__ anchors,
                         const int* __restrict__ flag,
                         float* __restrict__ boxes) {
    int i = blockIdx.x * blockDim.x + threadIdx.x;
    if (i >= B_N * A_N) return;
    int bf = flag[0];
    int a = i % A_N;
    float ax1 = ldin(anchors, (size_t)a * 4 + 0, bf);
    float ay1 = ldin(anchors, (size_t)a * 4 + 1, bf);
    float ax2 = ldin(anchors, (size_t)a * 4 + 2, bf);
    float ay2 = ldin(anchors, (size_t)a * 4 + 3, bf);
    float r0 = ldin(rel, (size_t)i * 4 + 0, bf);
    float r1 = ldin(rel, (size_t)i * 4 + 1, bf);
    float r2 = ldin(rel, (size_t)i * 4 + 2, bf);
    float r3 = ldin(rel, (size_t)i * 4 + 3, bf);
    float wa = ax2 - ax1, ha = ay2 - ay1;
    float cxa = ax1 + 0.5f * wa, cya = ay1 + 0.5f * ha;
    float dx = r0 / 10.0f, dy = r1 / 10.0f;
    float dw = fminf(r2 / 5.0f, BBOX_CLIPF);
    float dh = fminf(r3 / 5.0f, BBOX_CLIPF);
    float cx = dx * wa + cxa, cy = dy * ha + cya;
    float w = np_expf(dw) * wa, h = np_expf(dh) * ha;
    float* o = boxes + (size_t)i * 4;
    o[0] = fminf(fmaxf(cx - 0.5f * w, 0.0f), 300.0f);
    o[1] = fminf(fmaxf(cy - 0.5f * h, 0.0f), 300.0f);
    o[2] = fminf(fmaxf(cx + 0.5f * w, 0.0f), 300.0f);
    o[3] = fminf(fmaxf(cy + 0.5f * h, 0.0f), 300.0f);
}

// ---------------------------------------------------------------- exact per-class top-400
// Radix-select over all 8732 masked scores; stable ties: lowest anchor first,
// boundary ties keep smallest anchors (np.argsort(-x, kind='stable') twin).
__global__ __launch_bounds__(1024) void k_topk(const void* __restrict__ logits,
                                               const int* __restrict__ flag,
                                               const float* __restrict__ amax,
                                               const float* __restrict__ denom,
                                               unsigned long long* __restrict__ gkey,
                                               int* __restrict__ cAnchor) {
    __shared__ unsigned sbits[A_N];          // 34928 B
    __shared__ int wred[16];
    __shared__ unsigned bcast_p;
    __shared__ int bcast_rem;
    __shared__ int eqlist[64];
    __shared__ int eqn;
    __shared__ int bcast_athr;
    __shared__ unsigned long long wlist[512];
    __shared__ int nsel;

    int bc = blockIdx.x;
    int b  = bc / CM1;
    int cm = bc % CM1;                       // class row 0..89 (logit col cm+1)
    int bf = flag[0];
    int t  = threadIdx.x;

    // masked score bits (np exp / np pairwise denom — np-f32-exact)
    for (int a = t; a < A_N; a += 1024) {
        size_t base = (size_t)b * A_N + a;
        float e  = np_expf(ldin(logits, base * C_N + (cm + 1), bf) - amax[base]);
        float sc = e / denom[base];
        sbits[a] = (sc > 0.01f) ? __float_as_uint(sc) : 0u;
    }
    if (t == 0) { eqn = 0; nsel = 0; }
    __syncthreads();

    // count of real (above-threshold) entries
    {
        int c0 = 0;
        for (int a = t; a < A_N; a += 1024) c0 += (sbits[a] != 0u);
        for (int o = 32; o; o >>= 1) c0 += __shfl_down(c0, o);
        if ((t & 63) == 0) wred[t >> 6] = c0;
        __syncthreads();
        if (t == 0) {
            int tot = 0;
            for (int wv = 0; wv < 16; ++wv) tot += wred[wv];
            bcast_rem = tot;
        }
        __syncthreads();
    }
    int nreal = bcast_rem;
    __syncthreads();

    unsigned sstar = 0u;
    int teq = 0;
    if (nreal >= TOPK) {
        // MSB-first radix select of the 400th largest; scores in (0.01,1)
        // share top-6 bits 001111 -> start at bit 25.
        unsigned p = 0x3C000000u;
        int rem = TOPK;
        for (int bit = 25; bit >= 0; --bit) {
            unsigned q = p | (1u << bit);
            int cnt = 0;
            for (int a = t; a < A_N; a += 1024) cnt += ((sbits[a] >> bit) == (q >> bit));
            for (int o = 32; o; o >>= 1) cnt += __shfl_down(cnt, o);
            if ((t & 63) == 0) wred[t >> 6] = cnt;
            __syncthreads();
            if (t == 0) {
                int tot = 0;
                for (int wv = 0; wv < 16; ++wv) tot += wred[wv];
                if (tot >= rem) { bcast_p = q; bcast_rem = rem; }
                else            { bcast_p = p; bcast_rem = rem - tot; }
            }
            __syncthreads();
            p = bcast_p; rem = bcast_rem;
            __syncthreads();
        }
        sstar = p;
        teq = rem;                           // ==sstar ties to take (smallest anchors)
        for (int a = t; a < A_N; a += 1024) {
            if (sbits[a] == sstar) {
                int slot = atomicAdd(&eqn, 1);
                if (slot < 64) eqlist[slot] = a;
            }
        }
        __syncthreads();
        if (t == 0) {
            int n = eqn < 64 ? eqn : 64;
            for (int i = 1; i < n; ++i) {
                int v = eqlist[i], j = i - 1;
                while (j >= 0 && eqlist[j] > v) { eqlist[j + 1] = eqlist[j]; --j; }
                eqlist[j + 1] = v;
            }
            int tq = teq < n ? teq : n;
            bcast_athr = (tq > 0) ? eqlist[tq - 1] : -1;
        }
        __syncthreads();
    }
    int athr = (nreal >= TOPK) ? bcast_athr : -1;
    __syncthreads();

    for (int a = t; a < A_N; a += 1024) {
        unsigned v = sbits[a];
        bool sel;
        if (nreal >= TOPK)
            sel = (v > sstar) || (v == sstar && a <= athr);
        else
            sel = (v != 0u);
        if (sel) {
            int slot = atomicAdd(&nsel, 1);
            if (slot < 512)
                wlist[slot] = ((unsigned long long)v << 32) | (unsigned)(~(unsigned)a);
        }
    }
    __syncthreads();
    int ns = nsel < 512 ? nsel : 512;
    for (int i = t; i < 512; i += 1024)
        if (i >= ns) wlist[i] = 0ull;
    __syncthreads();

    // bitonic sort 512 desc (score desc, anchor asc via ~a)
    for (int k = 2; k <= 512; k <<= 1) {
        for (int j = k >> 1; j > 0; j >>= 1) {
            for (int i = t; i < 512; i += 1024) {
                int ixj = i ^ j;
                if (ixj > i) {
                    unsigned long long u = wlist[i], v = wlist[ixj];
                    bool desc = ((i & k) == 0);
                    if (desc ? (u < v) : (u > v)) { wlist[i] = v; wlist[ixj] = u; }
                }
            }
            __syncthreads();
        }
    }

    // emit flat candidates; global argmax ties -> smallest flat (np.argmax)
    for (int r = t; r < TOPK; r += 1024) {
        unsigned long long key = wlist[r];
        unsigned bits = (unsigned)(key >> 32);
        int flat = cm * TOPK + r;
        size_t gi = (size_t)b * NCAND + flat;
        gkey[gi] = bits ? (((unsigned long long)bits << 17) |
                           (unsigned long long)(131071 - flat))
                        : 0ull;
        cAnchor[gi] = (int)(~(unsigned)key);
    }
}

// ---------------------------------------------------------------- literal global greedy NMS
__global__ __launch_bounds__(1024) void k_greedy(unsigned long long* __restrict__ gkey,
                                                 const int* __restrict__ cAnchor,
                                                 const float* __restrict__ boxes,
                                                 float* __restrict__ out) {
    __shared__ unsigned long long wred64[16];
    __shared__ float pbox[4];
    __shared__ int pflat;

    int b = blockIdx.x;
    int t = threadIdx.x;
    unsigned long long* keys = gkey + (size_t)b * NCAND;
    const int* anc = cAnchor + (size_t)b * NCAND;
    const float* bx = boxes + (size_t)b * A_N * 4;
    float* ob = out + (size_t)b * MAXDET * 4;
    float* os = out + (size_t)B_N * MAXDET * 4 + (size_t)b * MAXDET;
    float* ol = out + (size_t)B_N * MAXDET * 5 + (size_t)b * MAXDET;

    for (int slot = 0; slot < MAXDET; ++slot) {
        unsigned long long mx = 0ull;
        for (int i = t; i < NCAND; i += 1024) {
            unsigned long long k = keys[i];
            if (k > mx) mx = k;
        }
        for (int o = 32; o; o >>= 1) {
            unsigned long long other = __shfl_down(mx, o);
            if (other > mx) mx = other;
        }
        if ((t & 63) == 0) wred64[t >> 6] = mx;
        __syncthreads();
        if (t == 0) {
            unsigned long long w = 0ull;
            for (int i = 0; i < 16; ++i)
                if (wred64[i] > w) w = wred64[i];
            if (w == 0ull) {
                pflat = -1;
                ob[slot * 4 + 0] = 0.0f; ob[slot * 4 + 1] = 0.0f;
                ob[slot * 4 + 2] = 0.0f; ob[slot * 4 + 3] = 0.0f;
                os[slot] = 0.0f; ol[slot] = 0.0f;
            } else {
                int flat = 131071 - (int)(w & 0x1FFFFull);
                int cls  = flat / TOPK;          // 0..89
                int a    = anc[flat];
                float offc = (float)(cls + 1) * 301.0f;
                const float* bp = bx + (size_t)a * 4;
                ob[slot * 4 + 0] = bp[0]; ob[slot * 4 + 1] = bp[1];
                ob[slot * 4 + 2] = bp[2]; ob[slot * 4 + 3] = bp[3];
                os[slot] = __uint_as_float((unsigned)(w >> 17));
                ol[slot] = (float)(cls + 1);
                keys[flat] = 0ull;
                pbox[0] = bp[0] + offc; pbox[1] = bp[1] + offc;
                pbox[2] = bp[2] + offc; pbox[3] = bp[3] + offc;
                pflat = flat;
            }
        }
        __syncthreads();
        int pf = pflat;
        if (pf >= 0 && t < TOPK) {
            int cls = pf / TOPK;
            int j = cls * TOPK + t;
            unsigned long long kj = keys[j];
            if (kj != 0ull) {
                float offc = (float)(cls + 1) * 301.0f;
                const float* bq = bx + (size_t)anc[j] * 4;
                float x1 = bq[0] + offc, y1 = bq[1] + offc;
                float x2 = bq[2] + offc, y2 = bq[3] + offc;
                float lx = fmaxf(pbox[0], x1), ly = fmaxf(pbox[1], y1);
                float rx = fminf(pbox[2], x2), ry = fminf(pbox[3], y2);
                float ww = fmaxf(rx - lx, 0.0f), hh = fmaxf(ry - ly, 0.0f);
                float inter = ww * hh;
                float a1 = (pbox[2] - pbox[0]) * (pbox[3] - pbox[1]);
                float a2 = (x2 - x1) * (y2 - y1);
                float iou = inter / (a1 + a2 - inter + 1e-9f);
                if (iou > 0.45f) keys[j] = 0ull;
            }
        }
        __syncthreads();
    }
}

// ---------------------------------------------------------------- host launcher
extern "C" void kernel_launch(void* const* d_in, const int* in_sizes, int n_in,
                              void* d_out, int out_size, void* d_ws, size_t ws_size,
                              hipStream_t stream) {
    const void* logits  = d_in[0];   // [32, 8732, 91] f32
    const void* rel     = d_in[1];   // [32, 8732, 4]
    const void* anchors = d_in[2];   // [8732, 4]
    float* out = (float*)d_out;      // boxes|scores|labels flat, f32

    char* ws = (char*)d_ws;
    size_t off = 0;
    auto alloc = [&](size_t bytes) -> void* {
        void* p = ws + off;
        off = (off + bytes + 255) & ~(size_t)255;
        return p;
    };
    float* boxes  = (float*)alloc((size_t)B_N * A_N * 4 * sizeof(float));
    float* amax   = (float*)alloc((size_t)B_N * A_N * sizeof(float));
    float* denom  = (float*)alloc((size_t)B_N * A_N * sizeof(float));
    int*   flag   = (int*)alloc(256);
    unsigned long long* gkey = (unsigned long long*)alloc((size_t)B_N * NCAND * sizeof(unsigned long long));
    int* cAnchor  = (int*)alloc((size_t)B_N * NCAND * sizeof(int));

    int gridBA = (B_N * A_N + 255) / 256;

    k_sniff<<<1, 256, 0, stream>>>((const unsigned*)logits, flag);
    k_stats<<<gridBA, 256, 0, stream>>>(logits, flag, amax, denom);
    k_decode<<<gridBA, 256, 0, stream>>>(rel, anchors, flag, boxes);
    k_topk<<<B_N * CM1, 1024, 0, stream>>>(logits, flag, amax, denom, gkey, cAnchor);
    k_greedy<<<B_N, 1024, 0, stream>>>(gkey, cAnchor, boxes, out);
}

// Round 11
// 1314.606 us; speedup vs baseline: 1.4921x; 1.4921x over previous
//
#include <hip/hip_runtime.h>
#include <hip/hip_bf16.h>
#include <cstdint>
#include <cstddef>
#include <math.h>

// Match numpy f32 per-op rounding: no FMA contraction, no reassociation.
// (fmaf() below is explicit and unaffected by the pragma.)
#pragma clang fp contract(off)

#define A_N 8732
#define C_N 91
#define CM1 90
#define B_N 32
#define TOPK 400
#define MAXDET 200
#define NT 512                              /* threads in k_topknms */
#define BBOX_CLIPF 4.135166556742356f       /* log(1000/16) cast to f32 */

// Dual-path input load (reference is float32; sniff is insurance).
__device__ __forceinline__ float ldin(const void* p, size_t i, int isbf16) {
    if (isbf16) return __bfloat162float(((const __hip_bfloat16*)p)[i]);
    return ((const float*)p)[i];
}

// numpy SIMD f32 exp — bit-faithful (PROVEN bit-exact in round 10, absmax 0.0).
// DO NOT alter any constant or association.
__device__ __forceinline__ float np_expf(float x) {
    float q = rintf(x * 1.442695040f);
    float r = fmaf(q, -0.693359375f, x);
    r = fmaf(q, 2.12194440e-4f, r);
    float p = 1.9875691500E-4f;
    p = fmaf(p, r, 1.3981999507E-3f);
    p = fmaf(p, r, 8.3334519073E-3f);
    p = fmaf(p, r, 4.1665795894E-2f);
    p = fmaf(p, r, 1.6666665459E-1f);
    p = fmaf(p, r, 5.0000001201E-1f);
    p = fmaf(p, r, 1.0f);
    p = fmaf(p, r, 1.0f);
    return ldexpf(p, (int)q);
}

// ---------------------------------------------------------------- dtype sniff
__global__ void k_sniff(const unsigned* __restrict__ words, int* __restrict__ flag) {
    __shared__ int cnt_s;
    if (threadIdx.x == 0) cnt_s = 0;
    __syncthreads();
    int local = 0;
    for (int i = threadIdx.x; i < 4096; i += 256) {
        unsigned w = words[i];
        unsigned e = (w >> 7) & 0xFFu;
        if (e >= 100u && e <= 140u) local++;
    }
    atomicAdd(&cnt_s, local);
    __syncthreads();
    if (threadIdx.x == 0) flag[0] = (cnt_s > 2048) ? 1 : 0;
}

// ---------------------------------------------------------------- softmax stats
// denom = numpy pairwise_sum over the 91 f32 exp terms (PROVEN bit-exact r10).
__global__ void k_stats(const void* __restrict__ logits,
                        const int* __restrict__ flag,
                        float* __restrict__ amax,
                        float* __restrict__ denom) {
    int i = blockIdx.x * blockDim.x + threadIdx.x;
    if (i >= B_N * A_N) return;
    int bf = flag[0];
    size_t base = (size_t)i * C_N;
    float m = -INFINITY;
    for (int c = 0; c < C_N; ++c) m = fmaxf(m, ldin(logits, base + c, bf));
    float r[8];
    for (int j = 0; j < 8; ++j) r[j] = np_expf(ldin(logits, base + j, bf) - m);
    for (int c = 8; c < 88; c += 8)
        for (int j = 0; j < 8; ++j) r[j] += np_expf(ldin(logits, base + c + j, bf) - m);
    float res = ((r[0] + r[1]) + (r[2] + r[3])) + ((r[4] + r[5]) + (r[6] + r[7]));
    res += np_expf(ldin(logits, base + 88, bf) - m);
    res += np_expf(ldin(logits, base + 89, bf) - m);
    res += np_expf(ldin(logits, base + 90, bf) - m);
    amax[i]  = m;
    denom[i] = res;
}

// ---------------------------------------------------------------- box decode (PROVEN bit-exact r10)
__global__ void k_decode(const void* __restrict__ rel,
                         const void* __restrict__ anchors,
                         const int* __restrict__ flag,
                         float* __restrict__ boxes) {
    int i = blockIdx.x * blockDim.x + threadIdx.x;
    if (i >= B_N * A_N) return;
    int bf = flag[0];
    int a = i % A_N;
    float ax1 = ldin(anchors, (size_t)a * 4 + 0, bf);
    float ay1 = ldin(anchors, (size_t)a * 4 + 1, bf);
    float ax2 = ldin(anchors, (size_t)a * 4 + 2, bf);
    float ay2 = ldin(anchors, (size_t)a * 4 + 3, bf);
    float r0 = ldin(rel, (size_t)i * 4 + 0, bf);
    float r1 = ldin(rel, (size_t)i * 4 + 1, bf);
    float r2 = ldin(rel, (size_t)i * 4 + 2, bf);
    float r3 = ldin(rel, (size_t)i * 4 + 3, bf);
    float wa = ax2 - ax1, ha = ay2 - ay1;
    float cxa = ax1 + 0.5f * wa, cya = ay1 + 0.5f * ha;
    float dx = r0 / 10.0f, dy = r1 / 10.0f;
    float dw = fminf(r2 / 5.0f, BBOX_CLIPF);
    float dh = fminf(r3 / 5.0f, BBOX_CLIPF);
    float cx = dx * wa + cxa, cy = dy * ha + cya;
    float w = np_expf(dw) * wa, h = np_expf(dh) * ha;
    float* o = boxes + (size_t)i * 4;
    o[0] = fminf(fmaxf(cx - 0.5f * w, 0.0f), 300.0f);
    o[1] = fminf(fmaxf(cy - 0.5f * h, 0.0f), 300.0f);
    o[2] = fminf(fmaxf(cx + 0.5f * w, 0.0f), 300.0f);
    o[3] = fminf(fmaxf(cy + 0.5f * h, 0.0f), 300.0f);
}

// ---------------------------------------------------------------- fused top-400 + per-class NMS
// r10's proven radix-select + bitonic sort (adapted 1024->512 threads), then
// per-class greedy NMS in-block (output-equivalent to the literal global scan:
// cross-class suppression is exactly zero due to >=301 class offsets; proven
// empirically r1-r4 vs r5-r9 bit-identical outputs). Emits <=200 kept keys:
//   key = (score_bits<<31) | ((131071-flat)<<14) | anchor
// whose descending order == r10's global argmax pick order.
__global__ __launch_bounds__(NT) void k_topknms(const void* __restrict__ logits,
                                                const int* __restrict__ flag,
                                                const float* __restrict__ amax,
                                                const float* __restrict__ denom,
                                                const float* __restrict__ boxes,
                                                unsigned long long* __restrict__ kkey,
                                                int* __restrict__ kcnt) {
    __shared__ union {
        unsigned sbits[A_N];                 // 34928 B (phase 1: scores)
        unsigned long long msk[TOPK * 7];    // 22400 B (phase 2: NMS bitmask)
    } su;
    __shared__ unsigned long long wlist[512];
    __shared__ float bx1[TOPK], by1[TOPK], bx2[TOPK], by2[TOPK], bar[TOPK];
    __shared__ int wred[NT / 64];
    __shared__ unsigned bcast_p;
    __shared__ int bcast_rem;
    __shared__ int eqlist[64];
    __shared__ int eqn;
    __shared__ int bcast_athr;
    __shared__ int nsel;

    int bc = blockIdx.x;
    int b  = bc / CM1;
    int cm = bc % CM1;                       // class row 0..89 (logit col cm+1)
    int bf = flag[0];
    int t  = threadIdx.x;

    // masked score bits (np exp / np pairwise denom — bit-exact r10 expressions)
    for (int a = t; a < A_N; a += NT) {
        size_t base = (size_t)b * A_N + a;
        float e  = np_expf(ldin(logits, base * C_N + (cm + 1), bf) - amax[base]);
        float sc = e / denom[base];
        su.sbits[a] = (sc > 0.01f) ? __float_as_uint(sc) : 0u;
    }
    if (t == 0) { eqn = 0; nsel = 0; }
    __syncthreads();

    // count of real (above-threshold) entries
    {
        int c0 = 0;
        for (int a = t; a < A_N; a += NT) c0 += (su.sbits[a] != 0u);
        for (int o = 32; o; o >>= 1) c0 += __shfl_down(c0, o);
        if ((t & 63) == 0) wred[t >> 6] = c0;
        __syncthreads();
        if (t == 0) {
            int tot = 0;
            for (int wv = 0; wv < NT / 64; ++wv) tot += wred[wv];
            bcast_rem = tot;
        }
        __syncthreads();
    }
    int nreal = bcast_rem;
    __syncthreads();

    unsigned sstar = 0u;
    int teq = 0;
    if (nreal >= TOPK) {
        // MSB-first bit-serial radix select of the 400th largest (proven r10).
        unsigned p = 0x3C000000u;
        int rem = TOPK;
        for (int bit = 25; bit >= 0; --bit) {
            unsigned q = p | (1u << bit);
            int cnt = 0;
            for (int a = t; a < A_N; a += NT) cnt += ((su.sbits[a] >> bit) == (q >> bit));
            for (int o = 32; o; o >>= 1) cnt += __shfl_down(cnt, o);
            if ((t & 63) == 0) wred[t >> 6] = cnt;
            __syncthreads();
            if (t == 0) {
                int tot = 0;
                for (int wv = 0; wv < NT / 64; ++wv) tot += wred[wv];
                if (tot >= rem) { bcast_p = q; bcast_rem = rem; }
                else            { bcast_p = p; bcast_rem = rem - tot; }
            }
            __syncthreads();
            p = bcast_p; rem = bcast_rem;
            __syncthreads();
        }
        sstar = p;
        teq = rem;                           // ==sstar ties to take (smallest anchors)
        for (int a = t; a < A_N; a += NT) {
            if (su.sbits[a] == sstar) {
                int slot = atomicAdd(&eqn, 1);
                if (slot < 64) eqlist[slot] = a;
            }
        }
        __syncthreads();
        if (t == 0) {
            int n = eqn < 64 ? eqn : 64;
            for (int i = 1; i < n; ++i) {
                int v = eqlist[i], j = i - 1;
                while (j >= 0 && eqlist[j] > v) { eqlist[j + 1] = eqlist[j]; --j; }
                eqlist[j + 1] = v;
            }
            int tq = teq < n ? teq : n;
            bcast_athr = (tq > 0) ? eqlist[tq - 1] : -1;
        }
        __syncthreads();
    }
    int athr = (nreal >= TOPK) ? bcast_athr : -1;
    __syncthreads();

    for (int a = t; a < A_N; a += NT) {
        unsigned v = su.sbits[a];
        bool sel;
        if (nreal >= TOPK)
            sel = (v > sstar) || (v == sstar && a <= athr);
        else
            sel = (v != 0u);
        if (sel) {
            int slot = atomicAdd(&nsel, 1);
            if (slot < 512)
                wlist[slot] = ((unsigned long long)v << 32) | (unsigned)(~(unsigned)a);
        }
    }
    __syncthreads();
    int ns = nsel < 512 ? nsel : 512;
    if (t < 512 && t >= ns) wlist[t] = 0ull;
    __syncthreads();

    // bitonic sort 512 desc (score desc, anchor asc via ~a) — proven r10
    for (int k = 2; k <= 512; k <<= 1) {
        for (int j = k >> 1; j > 0; j >>= 1) {
            int ixj = t ^ j;
            if (ixj > t) {
                unsigned long long u = wlist[t], v = wlist[ixj];
                bool desc = ((t & k) == 0);
                if (desc ? (u < v) : (u > v)) { wlist[t] = v; wlist[ixj] = u; }
            }
            __syncthreads();
        }
    }

    // ---- per-class NMS on the sorted top-400 (IoU bits identical to r10) ----
    int m = ns < TOPK ? ns : TOPK;
    float offc = (float)(cm + 1) * 301.0f;
    if (t < m) {
        unsigned aidx = ~(unsigned)(wlist[t] & 0xFFFFFFFFull);
        const float* bp = boxes + ((size_t)b * A_N + aidx) * 4;
        float x1 = bp[0] + offc, y1 = bp[1] + offc;   // same expr as r10 suppression
        float x2 = bp[2] + offc, y2 = bp[3] + offc;
        bx1[t] = x1; by1[t] = y1; bx2[t] = x2; by2[t] = y2;
        bar[t] = (x2 - x1) * (y2 - y1);
    }
    __syncthreads();   // last read of su.sbits was above; safe to reuse union

    if (t < m) {
        unsigned long long w[7] = {0, 0, 0, 0, 0, 0, 0};
        float x1 = bx1[t], y1 = by1[t], x2 = bx2[t], y2 = by2[t], a1 = bar[t];
        for (int j = t + 1; j < m; ++j) {
            float lx = fmaxf(x1, bx1[j]), ly = fmaxf(y1, by1[j]);
            float rx = fminf(x2, bx2[j]), ry = fminf(y2, by2[j]);
            float ww = fmaxf(rx - lx, 0.0f), hh = fmaxf(ry - ly, 0.0f);
            float inter = ww * hh;
            float iou = inter / (a1 + bar[j] - inter + 1e-9f);
            if (iou > 0.45f) w[j >> 6] |= 1ull << (j & 63);
        }
        for (int k2 = 0; k2 < 7; ++k2) su.msk[t * 7 + k2] = w[k2];
    }
    __syncthreads();

    if (t == 0) {
        unsigned long long sup[7] = {0, 0, 0, 0, 0, 0, 0};
        int cnt = 0;
        for (int i = 0; i < m; ++i) {
            if (!((sup[i >> 6] >> (i & 63)) & 1ull)) {
                unsigned long long wv = wlist[i];
                unsigned sb = (unsigned)(wv >> 32);
                unsigned a  = ~(unsigned)wv;              // anchor, <16384
                int flat = cm * TOPK + i;
                unsigned long long key =
                    ((unsigned long long)sb << 31) |
                    ((unsigned long long)(131071 - flat) << 14) |
                    (unsigned long long)a;
                kkey[(size_t)bc * MAXDET + cnt] = key;
                cnt++;
                if (cnt == MAXDET) break;
                const unsigned long long* r = &su.msk[i * 7];
                for (int k2 = 0; k2 < 7; ++k2) sup[k2] |= r[k2];
            }
        }
        kcnt[bc] = cnt;
    }
}

// ---------------------------------------------------------------- 90-way merge, 1 wave/image
// Kept lists are strictly key-descending; merge by key == r10's global argmax
// order (keys are globally unique: they embed flat). No __syncthreads needed —
// single wave64, shuffle reductions.
__global__ __launch_bounds__(64) void k_merge(const unsigned long long* __restrict__ kkey,
                                              const int* __restrict__ kcnt,
                                              const float* __restrict__ boxes,
                                              float* __restrict__ out) {
    int b = blockIdx.x;
    int t = threadIdx.x;
    const float* bx = boxes + (size_t)b * A_N * 4;
    float* ob = out + (size_t)b * MAXDET * 4;
    float* os = out + (size_t)B_N * MAXDET * 4 + (size_t)b * MAXDET;
    float* ol = out + (size_t)B_N * MAXDET * 5 + (size_t)b * MAXDET;

    int cls0 = t, cls1 = t + 64;
    int n0 = (cls0 < CM1) ? kcnt[b * CM1 + cls0] : 0;
    int n1 = (cls1 < CM1) ? kcnt[b * CM1 + cls1] : 0;
    const unsigned long long* l0 = kkey + (size_t)(b * CM1 + cls0) * MAXDET;
    const unsigned long long* l1 = kkey + (size_t)(b * CM1 + cls1) * MAXDET;
    int p0 = 0, p1 = 0;
    unsigned long long h0 = (n0 > 0) ? l0[0] : 0ull;
    unsigned long long h1 = (n1 > 0) ? l1[0] : 0ull;
    unsigned long long x0 = (n0 > 1) ? l0[1] : 0ull;   // prefetched next
    unsigned long long x1n = (n1 > 1) ? l1[1] : 0ull;

    for (int slot = 0; slot < MAXDET; ++slot) {
        unsigned long long m = h0 > h1 ? h0 : h1;
        for (int o = 32; o; o >>= 1) {
            unsigned long long v = __shfl_down(m, o);
            if (v > m) m = v;
        }
        m = __shfl(m, 0);                    // broadcast winner key
        if (m == 0ull) {
            if (t == 0) {
                ob[slot * 4 + 0] = 0.0f; ob[slot * 4 + 1] = 0.0f;
                ob[slot * 4 + 2] = 0.0f; ob[slot * 4 + 3] = 0.0f;
                os[slot] = 0.0f; ol[slot] = 0.0f;
            }
        } else {
            if (h0 == m) {                   // unique winner (keys unique)
                int a = (int)(m & 0x3FFFull);
                const float* bp = bx + (size_t)a * 4;
                ob[slot * 4 + 0] = bp[0]; ob[slot * 4 + 1] = bp[1];
                ob[slot * 4 + 2] = bp[2]; ob[slot * 4 + 3] = bp[3];
                os[slot] = __uint_as_float((unsigned)(m >> 31));
                ol[slot] = (float)(cls0 + 1);
                p0++; h0 = x0;
                x0 = (p0 + 1 < n0) ? l0[p0 + 1] : 0ull;
            } else if (h1 == m) {
                int a = (int)(m & 0x3FFFull);
                const float* bp = bx + (size_t)a * 4;
                ob[slot * 4 + 0] = bp[0]; ob[slot * 4 + 1] = bp[1];
                ob[slot * 4 + 2] = bp[2]; ob[slot * 4 + 3] = bp[3];
                os[slot] = __uint_as_float((unsigned)(m >> 31));
                ol[slot] = (float)(cls1 + 1);
                p1++; h1 = x1n;
                x1n = (p1 + 1 < n1) ? l1[p1 + 1] : 0ull;
            }
        }
    }
}

// ---------------------------------------------------------------- host launcher
extern "C" void kernel_launch(void* const* d_in, const int* in_sizes, int n_in,
                              void* d_out, int out_size, void* d_ws, size_t ws_size,
                              hipStream_t stream) {
    const void* logits  = d_in[0];   // [32, 8732, 91] f32
    const void* rel     = d_in[1];   // [32, 8732, 4]
    const void* anchors = d_in[2];   // [8732, 4]
    float* out = (float*)d_out;      // boxes|scores|labels flat, f32

    char* ws = (char*)d_ws;
    size_t off = 0;
    auto alloc = [&](size_t bytes) -> void* {
        void* p = ws + off;
        off = (off + bytes + 255) & ~(size_t)255;
        return p;
    };
    float* boxes  = (float*)alloc((size_t)B_N * A_N * 4 * sizeof(float));
    float* amax   = (float*)alloc((size_t)B_N * A_N * sizeof(float));
    float* denom  = (float*)alloc((size_t)B_N * A_N * sizeof(float));
    int*   flag   = (int*)alloc(256);
    unsigned long long* kkey = (unsigned long long*)alloc((size_t)B_N * CM1 * MAXDET * sizeof(unsigned long long));
    int* kcnt     = (int*)alloc((size_t)B_N * CM1 * sizeof(int));

    int gridBA = (B_N * A_N + 255) / 256;

    k_sniff<<<1, 256, 0, stream>>>((const unsigned*)logits, flag);
    k_stats<<<gridBA, 256, 0, stream>>>(logits, flag, amax, denom);
    k_decode<<<gridBA, 256, 0, stream>>>(rel, anchors, flag, boxes);
    k_topknms<<<B_N * CM1, NT, 0, stream>>>(logits, flag, amax, denom, boxes, kkey, kcnt);
    k_merge<<<B_N, 64, 0, stream>>>(kkey, kcnt, boxes, out);
}